// Round 5
// baseline (226.569 us; speedup 1.0000x reference)
//
#include <hip/hip_runtime.h>
#include <cstdint>
#include <cstddef>

// Problem constants
#define B_    2
#define S_    2048
#define H_    1024
#define NH_   16
#define HD_   64

typedef __attribute__((ext_vector_type(8))) __bf16 bf16x8;
typedef __attribute__((ext_vector_type(4))) __bf16 bf16x4;
typedef __attribute__((ext_vector_type(4))) float  f32x4;
typedef __attribute__((ext_vector_type(2))) unsigned u32x2;

typedef __attribute__((address_space(1))) const unsigned int gcu32_t;
typedef __attribute__((address_space(3))) unsigned int lu32_t;
#define GLOAD16(gp, lp) __builtin_amdgcn_global_load_lds((gcu32_t*)(gp), (lu32_t*)(lp), 16, 0, 0)

#if __has_builtin(__builtin_amdgcn_exp2f)
#define EXP2F(x) __builtin_amdgcn_exp2f(x)
#else
#define EXP2F(x) exp2f(x)
#endif

#define SC_Q 0.1803368977f   // 0.125 * log2(e), folded into Q at projection

__device__ __forceinline__ short f2bf(float f) {
  union { float f; unsigned u; } v; v.f = f;
  unsigned r = v.u + 0x7fffu + ((v.u >> 16) & 1u);   // RNE
  return (short)(r >> 16);
}

// ---------------------------------------------------------------------------
// Kernel 1: fp32 -> bf16 conversion of x and the four weight matrices.
// ---------------------------------------------------------------------------
__global__ __launch_bounds__(256) void convert_kernel(
    const float* __restrict__ x,  const float* __restrict__ wq,
    const float* __restrict__ wk, const float* __restrict__ wv,
    const float* __restrict__ wd,
    short* __restrict__ xb,  short* __restrict__ wqb, short* __restrict__ wkb,
    short* __restrict__ wvb, short* __restrict__ wdb) {
  size_t i = ((size_t)blockIdx.x * 256 + threadIdx.x) * 4;
  const float* src; short* dst; size_t off;
  if      (i < 4194304u) { src = x;  dst = xb;  off = i; }
  else if (i < 5242880u) { src = wq; dst = wqb; off = i - 4194304u; }
  else if (i < 6291456u) { src = wk; dst = wkb; off = i - 5242880u; }
  else if (i < 7340032u) { src = wv; dst = wvb; off = i - 6291456u; }
  else                   { src = wd; dst = wdb; off = i - 7340032u; }
  float4 v = *(const float4*)(src + off);
  short4 o; o.x = f2bf(v.x); o.y = f2bf(v.y); o.z = f2bf(v.z); o.w = f2bf(v.w);
  *(short4*)(dst + off) = o;
}

// ---------------------------------------------------------------------------
// Kernel 2/4: C[M,N] = A[M,K]*B[N,K]^T + bias, bf16, K=1024.  128x128 tile,
// 4 waves (2x2), 4x4 frags of 16x16x32 MFMA.  global_load_lds width=16 with
// XOR swizzle via pre-swizzled global source (rule 21).  No setprio (m190:
// null-to-negative on lockstep 2-barrier GEMM).
// MODE 0: QKV (z selects); Q output (z==0) is pre-scaled by SC_Q.
// MODE 1: fp32 store y = ctx@Wd^T + bd.
// ---------------------------------------------------------------------------
template<int MODE>
__global__ __launch_bounds__(256, 3) void gemm_bt(
    const short* __restrict__ A,
    const short* __restrict__ Bq, const short* __restrict__ Bk,
    const short* __restrict__ Bv,
    const float* __restrict__ biasq, const float* __restrict__ biask,
    const float* __restrict__ biasv,
    short* __restrict__ outq, short* __restrict__ outk, short* __restrict__ outv,
    float* __restrict__ outy) {
  __shared__ short As[128 * 64];
  __shared__ short Bs[128 * 64];

  const short* Bw; const float* bias; short* outs = nullptr;
  float qscale = 1.0f;
  if (MODE == 0) {
    int z = blockIdx.z;
    Bw   = (z == 0) ? Bq    : ((z == 1) ? Bk    : Bv);
    bias = (z == 0) ? biasq : ((z == 1) ? biask : biasv);
    outs = (z == 0) ? outq  : ((z == 1) ? outk  : outv);
    if (z == 0) qscale = SC_Q;
  } else {
    Bw = Bq; bias = biasq;
  }

  const int K = 1024;
  int tid  = threadIdx.x;
  int lane = tid & 63, w = tid >> 6;
  int wr = w >> 1, wc = w & 1;
  int m0 = blockIdx.y * 128, n0 = blockIdx.x * 128;
  int l15 = lane & 15, lg = lane >> 4;

  int lr = lane >> 3, lc8 = 8 * ((lane & 7) ^ lr);
  const short* Ag = A  + (size_t)(m0 + w * 8 + lr) * K + lc8;
  const short* Bg = Bw + (size_t)(n0 + w * 8 + lr) * K + lc8;

  int cxor = (l15 & 7) * 8;

  f32x4 acc[4][4];
  for (int m = 0; m < 4; m++)
    for (int n = 0; n < 4; n++) acc[m][n] = {0.f, 0.f, 0.f, 0.f};

  for (int kt = 0; kt < 16; kt++) {
    __syncthreads();
    for (int it = 0; it < 4; it++) {
      GLOAD16(Ag + (size_t)it * 32 * K + kt * 64, &As[(w * 8 + it * 32) * 64]);
      GLOAD16(Bg + (size_t)it * 32 * K + kt * 64, &Bs[(w * 8 + it * 32) * 64]);
    }
    __syncthreads();
#pragma unroll
    for (int kkh = 0; kkh < 2; kkh++) {
      int col = (kkh * 32 + lg * 8) ^ cxor;
      bf16x8 af[4], bfr[4];
#pragma unroll
      for (int m = 0; m < 4; m++)
        af[m] = *(const bf16x8*)&As[(wr * 64 + m * 16 + l15) * 64 + col];
#pragma unroll
      for (int n = 0; n < 4; n++)
        bfr[n] = *(const bf16x8*)&Bs[(wc * 64 + n * 16 + l15) * 64 + col];
#pragma unroll
      for (int m = 0; m < 4; m++)
#pragma unroll
        for (int n = 0; n < 4; n++)
          acc[m][n] = __builtin_amdgcn_mfma_f32_16x16x32_bf16(af[m], bfr[n], acc[m][n], 0, 0, 0);
    }
  }

  for (int n = 0; n < 4; n++) {
    int col = n0 + wc * 64 + n * 16 + l15;
    float bval = bias[col];
    if (MODE == 0) {
      int h = col >> 6, d = col & 63;
      for (int m = 0; m < 4; m++) {
        int rowb = m0 + wr * 64 + m * 16 + lg * 4;
        for (int j = 0; j < 4; j++) {
          int row = rowb + j;
          int bb = row >> 11, s = row & 2047;
          outs[(((size_t)bb * NH_ + h) * S_ + s) * HD_ + d] = f2bf((acc[m][n][j] + bval) * qscale);
        }
      }
    } else {
      for (int m = 0; m < 4; m++) {
        int rowb = m0 + wr * 64 + m * 16 + lg * 4;
        for (int j = 0; j < 4; j++)
          outy[(size_t)(rowb + j) * 1024 + col] = acc[m][n][j] + bval;
      }
    }
  }
}

// ---------------------------------------------------------------------------
// Kernel 3: flash attention, 8 waves x 16 q-rows (512 threads).
// Same tile geometry/LDS as round 4 (QTILE=128, KVTILE=64, 51.7KB) but
// 16 waves/CU resident instead of 8 -> softmax VALU chain of one wave
// overlaps another's MFMA phase.  Swapped-operand softmax (T12), defer-max
// (T13), hw transpose reads for V (T10), issue-early/write-late V (T14).
// ---------------------------------------------------------------------------
__global__ __launch_bounds__(512, 4) void attn_kernel(
    const short* __restrict__ Q, const short* __restrict__ K,
    const short* __restrict__ V, const float* __restrict__ mask,
    short* __restrict__ ctx) {
  __shared__ short QPs[128 * 72];       // Q staging (prologue) then Ps [q][72]
  __shared__ short Ks[2][64 * 64];
  __shared__ short Vs[2][64 * 64];      // subtiled: [kv/4][d/16][4][16]
  __shared__ float msk[2][64];

  int b = blockIdx.x;
  int bh = (b & 7) * 4 + ((b >> 3) >> 4);   // XCD-grouped: 4 heads per XCD
  int qb = (b >> 3) & 15;
  int bidx = bh >> 4, h = bh & 15;
  int q0 = qb * 128;
  int tid = threadIdx.x, lane = tid & 63, w = tid >> 6;   // w 0..7
  int l15 = lane & 15, lg = lane >> 4;

  const short* Qg = Q + (size_t)bh * S_ * HD_;
  const short* Kg = K + (size_t)bh * S_ * HD_;
  const short* Vg = V + (size_t)bh * S_ * HD_;

  int lr = lane >> 3, lc8 = 8 * ((lane & 7) ^ lr);
  int cxor = (l15 & 7) * 8;
  const float MLOG2E = -10000.0f * 1.442695041f;

  // ---- prologue: stage Q (swizzled), K tile 0, V tile 0, mask 0 ----
#pragma unroll
  for (int it = 0; it < 2; it++) {
    int r = w * 8 + it * 64;
    GLOAD16(Qg + (size_t)(q0 + r + lr) * HD_ + lc8, &QPs[r * 64]);
  }
  GLOAD16(Kg + (size_t)(w * 8 + lr) * HD_ + lc8, &Ks[0][(w * 8) * 64]);
  int vrow = tid >> 3, vcol = (tid & 7) * 8;   // vrow 0..63
  int voff = ((vrow >> 2) * 4 + (vcol >> 4)) * 64 + (vrow & 3) * 16 + (vcol & 15);
  *(int4*)&Vs[0][voff] = *(const int4*)&Vg[(size_t)vrow * HD_ + vcol];
  if (tid < 64) msk[0][tid] = (1.0f - mask[bidx * S_ + tid]) * MLOG2E;
  __syncthreads();

  // hoist Q fragments (B-operand: lane holds Q[q = w*16+l15][k-slice])
  bf16x8 qreg[2];
#pragma unroll
  for (int kkh = 0; kkh < 2; kkh++) {
    int row = w * 16 + l15;
    qreg[kkh] = *(const bf16x8*)&QPs[row * 64 + ((kkh * 32 + lg * 8) ^ cxor)];
  }
  __syncthreads();   // all waves done with QPs before it becomes Ps

  float mrun = -1e30f, lrun = 0.f;
  f32x4 oacc[4];
#pragma unroll
  for (int dt = 0; dt < 4; dt++) oacc[dt] = {0.f, 0.f, 0.f, 0.f};

  unsigned vtrbase = (unsigned)(uintptr_t)&Vs[0][0] + (unsigned)(lg * 1024 + l15 * 8);
  int psrow = (w * 16 + l15) * 72;

  for (int kt = 0; kt < 32; kt++) {
    int cur = kt & 1;

    // issue next-tile staging early (completes under this tile's compute)
    int4 vp0; float mp = 0.f;
    if (kt < 31) {
      const short* Kn = Kg + (size_t)(kt + 1) * 64 * HD_;
      GLOAD16(Kn + (size_t)(w * 8 + lr) * HD_ + lc8, &Ks[cur ^ 1][(w * 8) * 64]);
      const short* Vn = Vg + (size_t)(kt + 1) * 64 * HD_;
      vp0 = *(const int4*)&Vn[(size_t)vrow * HD_ + vcol];
      if (tid < 64) mp = (1.0f - mask[bidx * S_ + (kt + 1) * 64 + tid]) * MLOG2E;
    }

    // ---- S^T = mfma(K, Q): lane holds P[q=w*16+l15][k = n*16+lg*4+j] ----
    f32x4 sc[4];
#pragma unroll
    for (int n = 0; n < 4; n++) sc[n] = {0.f, 0.f, 0.f, 0.f};
    __builtin_amdgcn_s_setprio(1);
#pragma unroll
    for (int kkh = 0; kkh < 2; kkh++) {
      int col = (kkh * 32 + lg * 8) ^ cxor;
      bf16x8 kbf[4];
#pragma unroll
      for (int n = 0; n < 4; n++)
        kbf[n] = *(const bf16x8*)&Ks[cur][(n * 16 + l15) * 64 + col];
#pragma unroll
      for (int n = 0; n < 4; n++)
        sc[n] = __builtin_amdgcn_mfma_f32_16x16x32_bf16(kbf[n], qreg[kkh], sc[n], 0, 0, 0);
    }
    __builtin_amdgcn_s_setprio(0);

    // ---- mask add + per-q max (in-lane tree + 2 shfl) ----
    float pm[4];
#pragma unroll
    for (int n = 0; n < 4; n++) {
      f32x4 mv = *(const f32x4*)&msk[cur][n * 16 + lg * 4];
      float t0 = sc[n][0] + mv[0];
      float t1 = sc[n][1] + mv[1];
      float t2 = sc[n][2] + mv[2];
      float t3 = sc[n][3] + mv[3];
      sc[n][0] = t0; sc[n][1] = t1; sc[n][2] = t2; sc[n][3] = t3;
      pm[n] = fmaxf(fmaxf(t0, t1), fmaxf(t2, t3));
    }
    float rmax = fmaxf(fmaxf(pm[0], pm[1]), fmaxf(pm[2], pm[3]));
    rmax = fmaxf(rmax, __shfl_xor(rmax, 16));
    rmax = fmaxf(rmax, __shfl_xor(rmax, 32));

    // ---- defer-max rescale (T13, THR=8) ----
    if (__any(rmax > mrun + 8.f)) {
      float mn = fmaxf(mrun, rmax);
      float a = EXP2F(mrun - mn);
      lrun *= a;
      mrun = mn;
#pragma unroll
      for (int dt = 0; dt < 4; dt++)
#pragma unroll
        for (int j = 0; j < 4; j++) oacc[dt][j] *= a;
    }

    // ---- exp2 + in-lane sum ----
    float rs_ = 0.f;
#pragma unroll
    for (int n = 0; n < 4; n++)
#pragma unroll
      for (int j = 0; j < 4; j++) {
        float p = EXP2F(sc[n][j] - mrun);
        sc[n][j] = p;
        rs_ += p;
      }

    // ---- pack P to bf16, write [q][k] row (4 x ds_write_b64) ----
#pragma unroll
    for (int n = 0; n < 4; n++) {
      unsigned pk0, pk1;
      asm("v_cvt_pk_bf16_f32 %0, %1, %2" : "=v"(pk0) : "v"(sc[n][0]), "v"(sc[n][1]));
      asm("v_cvt_pk_bf16_f32 %0, %1, %2" : "=v"(pk1) : "v"(sc[n][2]), "v"(sc[n][3]));
      u32x2 wv2; wv2[0] = pk0; wv2[1] = pk1;
      *(u32x2*)&QPs[psrow + n * 16 + lg * 4] = wv2;
    }

    // cross-lane sum (off critical path; feeds lrun only)
    rs_ += __shfl_xor(rs_, 16);
    rs_ += __shfl_xor(rs_, 32);
    lrun += rs_;

    // ---- O^T += V^T P^T (V frags via hardware transpose reads) ----
    unsigned vtr = vtrbase + (unsigned)(cur * 8192);
#pragma unroll
    for (int kb2 = 0; kb2 < 2; kb2++) {
      bf16x4 vlo[4], vhi[4];
#pragma unroll
      for (int dt = 0; dt < 4; dt++) {
        unsigned a = vtr + (unsigned)(kb2 * 4096 + dt * 128);
        asm volatile("ds_read_b64_tr_b16 %0, %2\n\t"
                     "ds_read_b64_tr_b16 %1, %2 offset:512"
                     : "=v"(vlo[dt]), "=v"(vhi[dt]) : "v"(a));
      }
      bf16x8 pb = *(const bf16x8*)&QPs[psrow + kb2 * 32 + lg * 8];
      asm volatile("s_waitcnt lgkmcnt(0)" ::: "memory");
      __builtin_amdgcn_sched_barrier(0);
      __builtin_amdgcn_s_setprio(1);
#pragma unroll
      for (int dt = 0; dt < 4; dt++) {
        bf16x8 vb = __builtin_shufflevector(vlo[dt], vhi[dt], 0, 1, 2, 3, 4, 5, 6, 7);
        oacc[dt] = __builtin_amdgcn_mfma_f32_16x16x32_bf16(vb, pb, oacc[dt], 0, 0, 0);
      }
      __builtin_amdgcn_s_setprio(0);
    }

    // write-late staging for next tile, then the single barrier
    if (kt < 31) {
      *(int4*)&Vs[cur ^ 1][voff] = vp0;
      if (tid < 64) msk[cur ^ 1][tid] = mp;
    }
    __syncthreads();
  }

  // epilogue: lane holds O^T: q = q0+w*16+l15, d = dt*16+lg*4+j
  float inv = 1.0f / lrun;
  int sg = q0 + w * 16 + l15;
  size_t rowbase = ((size_t)(bidx * S_ + sg)) * H_ + h * HD_;
#pragma unroll
  for (int dt = 0; dt < 4; dt++) {
    short4 st;
    st.x = f2bf(oacc[dt][0] * inv);
    st.y = f2bf(oacc[dt][1] * inv);
    st.z = f2bf(oacc[dt][2] * inv);
    st.w = f2bf(oacc[dt][3] * inv);
    *(short4*)&ctx[rowbase + dt * 16 + lg * 4] = st;
  }
}

// ---------------------------------------------------------------------------
// Kernel 5: out = LayerNorm(y + x) * g + b, finite-masked.
// ---------------------------------------------------------------------------
__global__ __launch_bounds__(256) void ln_kernel(
    const float* __restrict__ y, const float* __restrict__ x,
    const float* __restrict__ g, const float* __restrict__ bta,
    float* __restrict__ out) {
  __shared__ float red[4];
  int row = blockIdx.x;
  int tid = threadIdx.x, lane = tid & 63, w = tid >> 6;
  size_t base = (size_t)row * 1024 + tid * 4;
  float4 yv = *(const float4*)(y + base);
  float4 xv = *(const float4*)(x + base);
  float v0 = yv.x + xv.x, v1 = yv.y + xv.y, v2 = yv.z + xv.z, v3 = yv.w + xv.w;

  float ssum = v0 + v1 + v2 + v3;
  for (int off = 1; off < 64; off <<= 1) ssum += __shfl_xor(ssum, off);
  if (lane == 0) red[w] = ssum;
  __syncthreads();
  float mean = (red[0] + red[1] + red[2] + red[3]) * (1.f / 1024.f);
  __syncthreads();

  float d0 = v0 - mean, d1 = v1 - mean, d2 = v2 - mean, d3 = v3 - mean;
  float sq = d0 * d0 + d1 * d1 + d2 * d2 + d3 * d3;
  for (int off = 1; off < 64; off <<= 1) sq += __shfl_xor(sq, off);
  if (lane == 0) red[w] = sq;
  __syncthreads();
  float var = (red[0] + red[1] + red[2] + red[3]) * (1.f / 1024.f);
  float rs = 1.0f / sqrtf(var + 1e-12f);

  int c = tid * 4;
  float4 gv = *(const float4*)(g + c);
  float4 bv = *(const float4*)(bta + c);
  float o0 = d0 * rs * gv.x + bv.x;
  float o1 = d1 * rs * gv.y + bv.y;
  float o2 = d2 * rs * gv.z + bv.z;
  float o3 = d3 * rs * gv.w + bv.w;
  float4 ov;
  ov.x = __builtin_isfinite(o0) ? o0 : 0.f;
  ov.y = __builtin_isfinite(o1) ? o1 : 0.f;
  ov.z = __builtin_isfinite(o2) ? o2 : 0.f;
  ov.w = __builtin_isfinite(o3) ? o3 : 0.f;
  *(float4*)(out + base) = ov;
}

// ---------------------------------------------------------------------------
extern "C" void kernel_launch(void* const* d_in, const int* in_sizes, int n_in,
                              void* d_out, int out_size, void* d_ws, size_t ws_size,
                              hipStream_t stream) {
  (void)in_sizes; (void)n_in; (void)out_size; (void)ws_size;
  const float* x    = (const float*)d_in[0];
  const float* mask = (const float*)d_in[1];
  const float* Wq   = (const float*)d_in[2];
  const float* bq   = (const float*)d_in[3];
  const float* Wk   = (const float*)d_in[4];
  const float* bk   = (const float*)d_in[5];
  const float* Wv   = (const float*)d_in[6];
  const float* bv   = (const float*)d_in[7];
  const float* Wd   = (const float*)d_in[8];
  const float* bd   = (const float*)d_in[9];
  const float* ln_g = (const float*)d_in[10];
  const float* ln_b = (const float*)d_in[11];
  float* out = (float*)d_out;

  char* ws = (char*)d_ws;
  short* xb   = (short*)(ws);                       //  8 MB  x bf16
  short* wqb  = (short*)(ws + ( 8ull << 20));       //  2 MB
  short* wkb  = (short*)(ws + (10ull << 20));       //  2 MB
  short* wvb  = (short*)(ws + (12ull << 20));       //  2 MB
  short* wdb  = (short*)(ws + (14ull << 20));       //  2 MB
  short* qb   = (short*)(ws + (16ull << 20));       //  8 MB  [B,NH,S,HD]
  short* kb   = (short*)(ws + (24ull << 20));       //  8 MB
  short* vb   = (short*)(ws + (32ull << 20));       //  8 MB
  short* ctxb = (short*)(ws + (40ull << 20));       //  8 MB  [B,S,H]
  float* y    = (float*)(ws + (48ull << 20));       // 16 MB  fp32

  convert_kernel<<<8192, 256, 0, stream>>>(x, Wq, Wk, Wv, Wd, xb, wqb, wkb, wvb, wdb);
  gemm_bt<0><<<dim3(8, 32, 3), 256, 0, stream>>>(xb, wqb, wkb, wvb, bq, bk, bv,
                                                 qb, kb, vb, nullptr);
  attn_kernel<<<512, 512, 0, stream>>>(qb, kb, vb, mask, ctxb);
  gemm_bt<1><<<dim3(8, 32, 1), 256, 0, stream>>>(ctxb, wdb, nullptr, nullptr, bd,
                                                 nullptr, nullptr, nullptr, nullptr,
                                                 nullptr, y);
  ln_kernel<<<4096, 256, 0, stream>>>(y, x, ln_g, ln_b, out);
}

// Round 6
// 218.753 us; speedup vs baseline: 1.0357x; 1.0357x over previous
//
#include <hip/hip_runtime.h>
#include <cstdint>
#include <cstddef>

// Problem constants
#define B_    2
#define S_    2048
#define H_    1024
#define NH_   16
#define HD_   64

typedef __attribute__((ext_vector_type(8)))  __bf16 bf16x8;
typedef __attribute__((ext_vector_type(4)))  __bf16 bf16x4;
typedef __attribute__((ext_vector_type(4)))  float  f32x4;
typedef __attribute__((ext_vector_type(16))) float  f32x16;
typedef __attribute__((ext_vector_type(4)))  unsigned u32x4;

typedef __attribute__((address_space(1))) const unsigned int gcu32_t;
typedef __attribute__((address_space(3))) unsigned int lu32_t;
#define GLOAD16(gp, lp) __builtin_amdgcn_global_load_lds((gcu32_t*)(gp), (lu32_t*)(lp), 16, 0, 0)

#if __has_builtin(__builtin_amdgcn_exp2f)
#define EXP2F(x) __builtin_amdgcn_exp2f(x)
#else
#define EXP2F(x) exp2f(x)
#endif

#define SC_Q 0.1803368977f   // 0.125 * log2(e), folded into Q at projection

__device__ __forceinline__ short f2bf(float f) {
  union { float f; unsigned u; } v; v.f = f;
  unsigned r = v.u + 0x7fffu + ((v.u >> 16) & 1u);   // RNE
  return (short)(r >> 16);
}

// ---------------------------------------------------------------------------
// Kernel 1: fp32 -> bf16 conversion of x and the four weight matrices.
// ---------------------------------------------------------------------------
__global__ __launch_bounds__(256) void convert_kernel(
    const float* __restrict__ x,  const float* __restrict__ wq,
    const float* __restrict__ wk, const float* __restrict__ wv,
    const float* __restrict__ wd,
    short* __restrict__ xb,  short* __restrict__ wqb, short* __restrict__ wkb,
    short* __restrict__ wvb, short* __restrict__ wdb) {
  size_t i = ((size_t)blockIdx.x * 256 + threadIdx.x) * 4;
  const float* src; short* dst; size_t off;
  if      (i < 4194304u) { src = x;  dst = xb;  off = i; }
  else if (i < 5242880u) { src = wq; dst = wqb; off = i - 4194304u; }
  else if (i < 6291456u) { src = wk; dst = wkb; off = i - 5242880u; }
  else if (i < 7340032u) { src = wv; dst = wvb; off = i - 6291456u; }
  else                   { src = wd; dst = wdb; off = i - 7340032u; }
  float4 v = *(const float4*)(src + off);
  short4 o; o.x = f2bf(v.x); o.y = f2bf(v.y); o.z = f2bf(v.z); o.w = f2bf(v.w);
  *(short4*)(dst + off) = o;
}

// ---------------------------------------------------------------------------
// Kernel 2/4: C[M,N] = A[M,K]*B[N,K]^T + bias, bf16, K=1024.  128x128 tile,
// 4 waves (2x2), 4x4 frags of 16x16x32 MFMA.  global_load_lds width=16 with
// XOR swizzle via pre-swizzled global source (rule 21).
// MODE 0: QKV (z selects); Q output (z==0) is pre-scaled by SC_Q.
// MODE 1: fp32 store y = ctx@Wd^T + bd.
// ---------------------------------------------------------------------------
template<int MODE>
__global__ __launch_bounds__(256, 3) void gemm_bt(
    const short* __restrict__ A,
    const short* __restrict__ Bq, const short* __restrict__ Bk,
    const short* __restrict__ Bv,
    const float* __restrict__ biasq, const float* __restrict__ biask,
    const float* __restrict__ biasv,
    short* __restrict__ outq, short* __restrict__ outk, short* __restrict__ outv,
    float* __restrict__ outy) {
  __shared__ short As[128 * 64];
  __shared__ short Bs[128 * 64];

  const short* Bw; const float* bias; short* outs = nullptr;
  float qscale = 1.0f;
  if (MODE == 0) {
    int z = blockIdx.z;
    Bw   = (z == 0) ? Bq    : ((z == 1) ? Bk    : Bv);
    bias = (z == 0) ? biasq : ((z == 1) ? biask : biasv);
    outs = (z == 0) ? outq  : ((z == 1) ? outk  : outv);
    if (z == 0) qscale = SC_Q;
  } else {
    Bw = Bq; bias = biasq;
  }

  const int K = 1024;
  int tid  = threadIdx.x;
  int lane = tid & 63, w = tid >> 6;
  int wr = w >> 1, wc = w & 1;
  int m0 = blockIdx.y * 128, n0 = blockIdx.x * 128;
  int l15 = lane & 15, lg = lane >> 4;

  int lr = lane >> 3, lc8 = 8 * ((lane & 7) ^ lr);
  const short* Ag = A  + (size_t)(m0 + w * 8 + lr) * K + lc8;
  const short* Bg = Bw + (size_t)(n0 + w * 8 + lr) * K + lc8;

  int cxor = (l15 & 7) * 8;

  f32x4 acc[4][4];
  for (int m = 0; m < 4; m++)
    for (int n = 0; n < 4; n++) acc[m][n] = {0.f, 0.f, 0.f, 0.f};

  for (int kt = 0; kt < 16; kt++) {
    __syncthreads();
    for (int it = 0; it < 4; it++) {
      GLOAD16(Ag + (size_t)it * 32 * K + kt * 64, &As[(w * 8 + it * 32) * 64]);
      GLOAD16(Bg + (size_t)it * 32 * K + kt * 64, &Bs[(w * 8 + it * 32) * 64]);
    }
    __syncthreads();
#pragma unroll
    for (int kkh = 0; kkh < 2; kkh++) {
      int col = (kkh * 32 + lg * 8) ^ cxor;
      bf16x8 af[4], bfr[4];
#pragma unroll
      for (int m = 0; m < 4; m++)
        af[m] = *(const bf16x8*)&As[(wr * 64 + m * 16 + l15) * 64 + col];
#pragma unroll
      for (int n = 0; n < 4; n++)
        bfr[n] = *(const bf16x8*)&Bs[(wc * 64 + n * 16 + l15) * 64 + col];
#pragma unroll
      for (int m = 0; m < 4; m++)
#pragma unroll
        for (int n = 0; n < 4; n++)
          acc[m][n] = __builtin_amdgcn_mfma_f32_16x16x32_bf16(af[m], bfr[n], acc[m][n], 0, 0, 0);
    }
  }

  for (int n = 0; n < 4; n++) {
    int col = n0 + wc * 64 + n * 16 + l15;
    float bval = bias[col];
    if (MODE == 0) {
      int h = col >> 6, d = col & 63;
      for (int m = 0; m < 4; m++) {
        int rowb = m0 + wr * 64 + m * 16 + lg * 4;
        for (int j = 0; j < 4; j++) {
          int row = rowb + j;
          int bb = row >> 11, s = row & 2047;
          outs[(((size_t)bb * NH_ + h) * S_ + s) * HD_ + d] = f2bf((acc[m][n][j] + bval) * qscale);
        }
      }
    } else {
      for (int m = 0; m < 4; m++) {
        int rowb = m0 + wr * 64 + m * 16 + lg * 4;
        for (int j = 0; j < 4; j++)
          outy[(size_t)(rowb + j) * 1024 + col] = acc[m][n][j] + bval;
      }
    }
  }
}

// ---------------------------------------------------------------------------
// Kernel 3: flash attention, 32x32x16 MFMA, softmax & P fully in registers.
//  - 4 waves x 32 q-rows (QTILE=128, KVBLK=64); q = lane&31, lh = lane>>5
//  - S^T = mfma_32x32x16(K_frag, Q_frag): lane holds 32 P-values for its q
//    (kv = kb*32 + 4*lh + (r&3) + 8*(r>>2)); reductions = in-lane tree +
//    one v_permlane32_swap_b32 (NO LDS, no bpermute)
//  - P -> PV B-frags in-register: per ks, 4 cvt_pk + 2 permlane32_swap
//    ({w0,w2}=swap(X0,X2), {w1,w3}=swap(X1,X3))  [T12]
//  - Q frags loaded straight from global (no Q LDS); K via global_load_lds
//    (XOR-swizzled); V subtiled in LDS, read via ds_read_b64_tr_b16 [T10]
//  - mask as 64-bit bitmask per tile (ballot-precomputed; all-ones fast path)
//  - defer-max (T13, THR=8); single barrier/tile; issue-early/write-late V
// ---------------------------------------------------------------------------
__global__ __launch_bounds__(256, 2) void attn_kernel(
    const short* __restrict__ Q, const short* __restrict__ K,
    const short* __restrict__ V, const float* __restrict__ mask,
    short* __restrict__ ctx) {
  __shared__ short Ks[2][64 * 64];
  __shared__ short Vs[2][64 * 64];     // subtiled: [kv/4][d/16][4][16]
  __shared__ unsigned long long mbits[32];

  int b = blockIdx.x;
  int bh = (b & 7) * 4 + ((b >> 3) >> 4);   // XCD-grouped
  int qb = (b >> 3) & 15;
  int bidx = bh >> 4, hh = bh & 15;
  int q0 = qb * 128;
  int tid = threadIdx.x, lane = tid & 63, w = tid >> 6;   // w 0..3
  int l31 = lane & 31, lh = lane >> 5, l15 = lane & 15;

  const short* Qg = Q + (size_t)bh * S_ * HD_;
  const short* Kg = K + (size_t)bh * S_ * HD_;
  const short* Vg = V + (size_t)bh * S_ * HD_;

  int lr = lane >> 3, lc8 = 8 * ((lane & 7) ^ lr);
  int kxor = (lane & 7) * 8;

  // ---- Q fragments straight from global: B-op, col q = w*32+l31,
  //      k-slice d = ks*16 + lh*8 + {0..7} ----
  const short* Qrow = Qg + (size_t)(q0 + w * 32 + l31) * HD_;
  bf16x8 qfrag[4];
#pragma unroll
  for (int ks = 0; ks < 4; ks++)
    qfrag[ks] = *(const bf16x8*)&Qrow[ks * 16 + lh * 8];

  // ---- prologue staging: K tile 0 (swizzled gload_lds), V tile 0, mask bits
  GLOAD16(Kg + (size_t)(w * 8 + lr) * HD_ + lc8, &Ks[0][(w * 8) * 64]);
  GLOAD16(Kg + (size_t)(w * 8 + 32 + lr) * HD_ + lc8, &Ks[0][(w * 8 + 32) * 64]);
  int vrow = tid >> 3, vcol = (tid & 7) * 8;   // vrow 0..31
  int voff = ((vrow >> 2) * 4 + (vcol >> 4)) * 64 + (vrow & 3) * 16 + (vcol & 15);
  *(int4*)&Vs[0][voff]        = *(const int4*)&Vg[(size_t)vrow * HD_ + vcol];
  *(int4*)&Vs[0][voff + 2048] = *(const int4*)&Vg[(size_t)(vrow + 32) * HD_ + vcol];
  if (w == 0) {
#pragma unroll 4
    for (int t = 0; t < 32; t++) {
      unsigned long long bb = __ballot(mask[bidx * S_ + t * 64 + lane] > 0.5f);
      if (lane == 0) mbits[t] = bb;
    }
  }
  __syncthreads();

  float mrun = -1e30f, lrun = 0.f;
  f32x16 oacc[2];
#pragma unroll
  for (int dt = 0; dt < 2; dt++)
#pragma unroll
    for (int j = 0; j < 16; j++) oacc[dt][j] = 0.f;

  // tr-read per-lane base: block(kvb,db)*128B + l15*8, db = dt*2+((lane>>4)&1),
  // kvb = 4ks + 2lh + jj  ->  + ks*2048 + dt*256 (+512 for jj=1 via offset)
  unsigned vtrb = (unsigned)(uintptr_t)&Vs[0][0]
                + (unsigned)(l15 * 8 + ((lane >> 4) & 1) * 128 + lh * 1024);

  for (int kt = 0; kt < 32; kt++) {
    int cur = kt & 1;

    // issue next-tile staging early (completes under this tile's compute)
    int4 vp0, vp1;
    if (kt < 31) {
      const short* Kn = Kg + (size_t)(kt + 1) * 64 * HD_;
      GLOAD16(Kn + (size_t)(w * 8 + lr) * HD_ + lc8, &Ks[cur ^ 1][(w * 8) * 64]);
      GLOAD16(Kn + (size_t)(w * 8 + 32 + lr) * HD_ + lc8, &Ks[cur ^ 1][(w * 8 + 32) * 64]);
      const short* Vn = Vg + (size_t)(kt + 1) * 64 * HD_;
      vp0 = *(const int4*)&Vn[(size_t)vrow * HD_ + vcol];
      vp1 = *(const int4*)&Vn[(size_t)(vrow + 32) * HD_ + vcol];
    }

    // ---- S^T = mfma(K, Q): sc[kb], lane q=l31, kv=kb*32+4lh+(r&3)+8(r>>2)
    f32x16 sc[2];
#pragma unroll
    for (int kb = 0; kb < 2; kb++)
#pragma unroll
      for (int j = 0; j < 16; j++) sc[kb][j] = 0.f;
    __builtin_amdgcn_s_setprio(1);
#pragma unroll
    for (int ks = 0; ks < 4; ks++)
#pragma unroll
      for (int kb = 0; kb < 2; kb++) {
        bf16x8 af = *(const bf16x8*)&Ks[cur][(kb * 32 + l31) * 64 + ((ks * 16 + lh * 8) ^ kxor)];
        sc[kb] = __builtin_amdgcn_mfma_f32_32x32x16_bf16(af, qfrag[ks], sc[kb], 0, 0, 0);
      }
    __builtin_amdgcn_s_setprio(0);

    // ---- mask (bitmask; all-ones tiles skip entirely) ----
    unsigned long long mb = mbits[kt];
    if (__any(mb != ~0ull)) {
      unsigned long long sh = mb >> (lh * 4);
#pragma unroll
      for (int kb = 0; kb < 2; kb++)
#pragma unroll
        for (int r = 0; r < 16; r++)
          if (!((sh >> (kb * 32 + (r & 3) + 8 * (r >> 2))) & 1)) sc[kb][r] = -1e30f;
    }

    // ---- per-q max: in-lane tree + one permlane32_swap ----
    float rmax = sc[0][0];
#pragma unroll
    for (int kb = 0; kb < 2; kb++)
#pragma unroll
      for (int r = 0; r < 16; r++) rmax = fmaxf(rmax, sc[kb][r]);
    {
      float xa = rmax, xb = rmax;
      asm volatile("v_permlane32_swap_b32 %0, %1" : "+v"(xa), "+v"(xb));
      rmax = fmaxf(xa, xb);
    }

    // ---- defer-max rescale (T13, THR=8) ----
    if (__any(rmax > mrun + 8.f)) {
      float mn = fmaxf(mrun, rmax);
      float a = EXP2F(mrun - mn);
      lrun *= a; mrun = mn;
#pragma unroll
      for (int dt = 0; dt < 2; dt++)
#pragma unroll
        for (int j = 0; j < 16; j++) oacc[dt][j] *= a;
    }

    // ---- exp2 + in-lane sum + permlane combine ----
    float rs_ = 0.f;
#pragma unroll
    for (int kb = 0; kb < 2; kb++)
#pragma unroll
      for (int r = 0; r < 16; r++) {
        float p = EXP2F(sc[kb][r] - mrun);
        sc[kb][r] = p;
        rs_ += p;
      }
    {
      float xa = rs_, xb = rs_;
      asm volatile("v_permlane32_swap_b32 %0, %1" : "+v"(xa), "+v"(xb));
      rs_ = xa + xb;
    }
    lrun += rs_;

    // ---- pack P -> PV B-frags in-register (4 cvt_pk + 2 swaps per ks) ----
    bf16x8 pfrag[4];
#pragma unroll
    for (int ks = 0; ks < 4; ks++) {
      int kb = ks >> 1, ro = (ks & 1) * 8;
      unsigned X0, X1, X2, X3;
      asm("v_cvt_pk_bf16_f32 %0, %1, %2" : "=v"(X0) : "v"(sc[kb][ro + 0]), "v"(sc[kb][ro + 1]));
      asm("v_cvt_pk_bf16_f32 %0, %1, %2" : "=v"(X1) : "v"(sc[kb][ro + 2]), "v"(sc[kb][ro + 3]));
      asm("v_cvt_pk_bf16_f32 %0, %1, %2" : "=v"(X2) : "v"(sc[kb][ro + 4]), "v"(sc[kb][ro + 5]));
      asm("v_cvt_pk_bf16_f32 %0, %1, %2" : "=v"(X3) : "v"(sc[kb][ro + 6]), "v"(sc[kb][ro + 7]));
      asm volatile("v_permlane32_swap_b32 %0, %1" : "+v"(X0), "+v"(X2));
      asm volatile("v_permlane32_swap_b32 %0, %1" : "+v"(X1), "+v"(X3));
      union { u32x4 u; bf16x8 b; } cvt;
      cvt.u[0] = X0; cvt.u[1] = X1; cvt.u[2] = X2; cvt.u[3] = X3;
      pfrag[ks] = cvt.b;
    }

    // ---- O^T += V^T P^T: V A-frags via tr-reads, per-dt batches ----
#pragma unroll
    for (int dt = 0; dt < 2; dt++) {
      bf16x4 vlo[4], vhi[4];
#pragma unroll
      for (int ks = 0; ks < 4; ks++) {
        unsigned a = vtrb + (unsigned)(cur * 8192 + ks * 2048 + dt * 256);
        asm volatile("ds_read_b64_tr_b16 %0, %2\n\t"
                     "ds_read_b64_tr_b16 %1, %2 offset:512"
                     : "=&v"(vlo[ks]), "=&v"(vhi[ks]) : "v"(a));
      }
      asm volatile("s_waitcnt lgkmcnt(0)" ::: "memory");
      __builtin_amdgcn_sched_barrier(0);
      __builtin_amdgcn_s_setprio(1);
#pragma unroll
      for (int ks = 0; ks < 4; ks++) {
        bf16x8 vb = __builtin_shufflevector(vlo[ks], vhi[ks], 0, 1, 2, 3, 4, 5, 6, 7);
        oacc[dt] = __builtin_amdgcn_mfma_f32_32x32x16_bf16(vb, pfrag[ks], oacc[dt], 0, 0, 0);
      }
      __builtin_amdgcn_s_setprio(0);
    }

    // write-late V staging for next tile, then the single barrier
    if (kt < 31) {
      *(int4*)&Vs[cur ^ 1][voff]        = vp0;
      *(int4*)&Vs[cur ^ 1][voff + 2048] = vp1;
    }
    __syncthreads();
  }

  // epilogue: lane holds O^T col q = q0+w*32+l31; d = dt*32 + 8*rr + 4*lh + j
  float inv = 1.0f / lrun;
  int q = q0 + w * 32 + l31;
  size_t base = ((size_t)(bidx * S_ + q)) * H_ + hh * HD_;
#pragma unroll
  for (int dt = 0; dt < 2; dt++)
#pragma unroll
    for (int rr = 0; rr < 4; rr++) {
      int d0 = dt * 32 + rr * 8 + lh * 4;
      short4 st;
      st.x = f2bf(oacc[dt][rr * 4 + 0] * inv);
      st.y = f2bf(oacc[dt][rr * 4 + 1] * inv);
      st.z = f2bf(oacc[dt][rr * 4 + 2] * inv);
      st.w = f2bf(oacc[dt][rr * 4 + 3] * inv);
      *(short4*)&ctx[base + d0] = st;
    }
}

// ---------------------------------------------------------------------------
// Kernel 5: out = LayerNorm(y + x) * g + b, finite-masked.
// ---------------------------------------------------------------------------
__global__ __launch_bounds__(256) void ln_kernel(
    const float* __restrict__ y, const float* __restrict__ x,
    const float* __restrict__ g, const float* __restrict__ bta,
    float* __restrict__ out) {
  __shared__ float red[4];
  int row = blockIdx.x;
  int tid = threadIdx.x, lane = tid & 63, w = tid >> 6;
  size_t base = (size_t)row * 1024 + tid * 4;
  float4 yv = *(const float4*)(y + base);
  float4 xv = *(const float4*)(x + base);
  float v0 = yv.x + xv.x, v1 = yv.y + xv.y, v2 = yv.z + xv.z, v3 = yv.w + xv.w;

  float ssum = v0 + v1 + v2 + v3;
  for (int off = 1; off < 64; off <<= 1) ssum += __shfl_xor(ssum, off);
  if (lane == 0) red[w] = ssum;
  __syncthreads();
  float mean = (red[0] + red[1] + red[2] + red[3]) * (1.f / 1024.f);
  __syncthreads();

  float d0 = v0 - mean, d1 = v1 - mean, d2 = v2 - mean, d3 = v3 - mean;
  float sq = d0 * d0 + d1 * d1 + d2 * d2 + d3 * d3;
  for (int off = 1; off < 64; off <<= 1) sq += __shfl_xor(sq, off);
  if (lane == 0) red[w] = sq;
  __syncthreads();
  float var = (red[0] + red[1] + red[2] + red[3]) * (1.f / 1024.f);
  float rs = 1.0f / sqrtf(var + 1e-12f);

  int c = tid * 4;
  float4 gv = *(const float4*)(g + c);
  float4 bv = *(const float4*)(bta + c);
  float o0 = d0 * rs * gv.x + bv.x;
  float o1 = d1 * rs * gv.y + bv.y;
  float o2 = d2 * rs * gv.z + bv.z;
  float o3 = d3 * rs * gv.w + bv.w;
  float4 ov;
  ov.x = __builtin_isfinite(o0) ? o0 : 0.f;
  ov.y = __builtin_isfinite(o1) ? o1 : 0.f;
  ov.z = __builtin_isfinite(o2) ? o2 : 0.f;
  ov.w = __builtin_isfinite(o3) ? o3 : 0.f;
  *(float4*)(out + base) = ov;
}

// ---------------------------------------------------------------------------
extern "C" void kernel_launch(void* const* d_in, const int* in_sizes, int n_in,
                              void* d_out, int out_size, void* d_ws, size_t ws_size,
                              hipStream_t stream) {
  (void)in_sizes; (void)n_in; (void)out_size; (void)ws_size;
  const float* x    = (const float*)d_in[0];
  const float* mask = (const float*)d_in[1];
  const float* Wq   = (const float*)d_in[2];
  const float* bq   = (const float*)d_in[3];
  const float* Wk   = (const float*)d_in[4];
  const float* bk   = (const float*)d_in[5];
  const float* Wv   = (const float*)d_in[6];
  const float* bv   = (const float*)d_in[7];
  const float* Wd   = (const float*)d_in[8];
  const float* bd   = (const float*)d_in[9];
  const float* ln_g = (const float*)d_in[10];
  const float* ln_b = (const float*)d_in[11];
  float* out = (float*)d_out;

  char* ws = (char*)d_ws;
  short* xb   = (short*)(ws);                       //  8 MB  x bf16
  short* wqb  = (short*)(ws + ( 8ull << 20));       //  2 MB
  short* wkb  = (short*)(ws + (10ull << 20));       //  2 MB
  short* wvb  = (short*)(ws + (12ull << 20));       //  2 MB
  short* wdb  = (short*)(ws + (14ull << 20));       //  2 MB
  short* qb   = (short*)(ws + (16ull << 20));       //  8 MB  [B,NH,S,HD]
  short* kb   = (short*)(ws + (24ull << 20));       //  8 MB
  short* vb   = (short*)(ws + (32ull << 20));       //  8 MB
  short* ctxb = (short*)(ws + (40ull << 20));       //  8 MB  [B,S,H]
  float* y    = (float*)(ws + (48ull << 20));       // 16 MB  fp32

  convert_kernel<<<8192, 256, 0, stream>>>(x, Wq, Wk, Wv, Wd, xb, wqb, wkb, wvb, wdb);
  gemm_bt<0><<<dim3(8, 32, 3), 256, 0, stream>>>(xb, wqb, wkb, wvb, bq, bk, bv,
                                                 qb, kb, vb, nullptr);
  attn_kernel<<<512, 256, 0, stream>>>(qb, kb, vb, mask, ctxb);
  gemm_bt<1><<<dim3(8, 32, 1), 256, 0, stream>>>(ctxb, wdb, nullptr, nullptr, bd,
                                                 nullptr, nullptr, nullptr, nullptr,
                                                 nullptr, y);
  ln_kernel<<<4096, 256, 0, stream>>>(y, x, ln_g, ln_b, out);
}

// Round 7
// 216.052 us; speedup vs baseline: 1.0487x; 1.0125x over previous
//
#include <hip/hip_runtime.h>
#include <cstdint>
#include <cstddef>

// Problem constants
#define B_    2
#define S_    2048
#define H_    1024
#define NH_   16
#define HD_   64

typedef __attribute__((ext_vector_type(8)))  __bf16 bf16x8;
typedef __attribute__((ext_vector_type(4)))  __bf16 bf16x4;
typedef __attribute__((ext_vector_type(4)))  float  f32x4;
typedef __attribute__((ext_vector_type(16))) float  f32x16;
typedef __attribute__((ext_vector_type(4)))  unsigned u32x4;

typedef __attribute__((address_space(1))) const unsigned int gcu32_t;
typedef __attribute__((address_space(3))) unsigned int lu32_t;
#define GLOAD16(gp, lp) __builtin_amdgcn_global_load_lds((gcu32_t*)(gp), (lu32_t*)(lp), 16, 0, 0)

#if __has_builtin(__builtin_amdgcn_exp2f)
#define EXP2F(x) __builtin_amdgcn_exp2f(x)
#else
#define EXP2F(x) exp2f(x)
#endif

#define SC_Q 0.1803368977f   // 0.125 * log2(e), folded into Q at projection

__device__ __forceinline__ short f2bf(float f) {
  union { float f; unsigned u; } v; v.f = f;
  unsigned r = v.u + 0x7fffu + ((v.u >> 16) & 1u);   // RNE
  return (short)(r >> 16);
}

// ---------------------------------------------------------------------------
// Kernel 1: fp32 -> bf16 conversion of x and the four weight matrices.
// ---------------------------------------------------------------------------
__global__ __launch_bounds__(256) void convert_kernel(
    const float* __restrict__ x,  const float* __restrict__ wq,
    const float* __restrict__ wk, const float* __restrict__ wv,
    const float* __restrict__ wd,
    short* __restrict__ xb,  short* __restrict__ wqb, short* __restrict__ wkb,
    short* __restrict__ wvb, short* __restrict__ wdb) {
  size_t i = ((size_t)blockIdx.x * 256 + threadIdx.x) * 4;
  const float* src; short* dst; size_t off;
  if      (i < 4194304u) { src = x;  dst = xb;  off = i; }
  else if (i < 5242880u) { src = wq; dst = wqb; off = i - 4194304u; }
  else if (i < 6291456u) { src = wk; dst = wkb; off = i - 5242880u; }
  else if (i < 7340032u) { src = wv; dst = wvb; off = i - 6291456u; }
  else                   { src = wd; dst = wdb; off = i - 7340032u; }
  float4 v = *(const float4*)(src + off);
  short4 o; o.x = f2bf(v.x); o.y = f2bf(v.y); o.z = f2bf(v.z); o.w = f2bf(v.w);
  *(short4*)(dst + off) = o;
}

// ---------------------------------------------------------------------------
// Kernel 2/4: C[M,N] = A[M,K]*B[N,K]^T (+bias), bf16.  128x128 tile, 4 waves,
// 4x4 frags of 16x16x32 MFMA.  global_load_lds width=16, XOR swizzle via
// pre-swizzled global source (rule 21).
// MODE 0: QKV (z selects W/bias/out; z==0 pre-scales by SC_Q); K=1024, KT=16.
// MODE 1: split-K out-proj: z = K-half (col offset z*512, KT=8), no bias,
//         fp32 partial to outy (z=0) / outy1 (z=1); bias folded into LN.
// ---------------------------------------------------------------------------
template<int MODE>
__global__ __launch_bounds__(256, 3) void gemm_bt(
    const short* __restrict__ A,
    const short* __restrict__ Bq, const short* __restrict__ Bk,
    const short* __restrict__ Bv,
    const float* __restrict__ biasq, const float* __restrict__ biask,
    const float* __restrict__ biasv,
    short* __restrict__ outq, short* __restrict__ outk, short* __restrict__ outv,
    float* __restrict__ outy, float* __restrict__ outy1) {
  __shared__ short As[128 * 64];
  __shared__ short Bs[128 * 64];

  const short* Bw; const float* bias = nullptr; short* outs = nullptr;
  float* youts = nullptr;
  float qscale = 1.0f;
  const int KT = (MODE == 0) ? 16 : 8;
  int koff = 0;
  if (MODE == 0) {
    int z = blockIdx.z;
    Bw   = (z == 0) ? Bq    : ((z == 1) ? Bk    : Bv);
    bias = (z == 0) ? biasq : ((z == 1) ? biask : biasv);
    outs = (z == 0) ? outq  : ((z == 1) ? outk  : outv);
    if (z == 0) qscale = SC_Q;
  } else {
    Bw = Bq;
    koff = blockIdx.z * 512;
    youts = (blockIdx.z == 0) ? outy : outy1;
  }

  const int K = 1024;
  int tid  = threadIdx.x;
  int lane = tid & 63, w = tid >> 6;
  int wr = w >> 1, wc = w & 1;
  int m0 = blockIdx.y * 128, n0 = blockIdx.x * 128;
  int l15 = lane & 15, lg = lane >> 4;

  int lr = lane >> 3, lc8 = 8 * ((lane & 7) ^ lr);
  const short* Ag = A  + (size_t)(m0 + w * 8 + lr) * K + lc8 + koff;
  const short* Bg = Bw + (size_t)(n0 + w * 8 + lr) * K + lc8 + koff;

  int cxor = (l15 & 7) * 8;

  f32x4 acc[4][4];
  for (int m = 0; m < 4; m++)
    for (int n = 0; n < 4; n++) acc[m][n] = {0.f, 0.f, 0.f, 0.f};

  for (int kt = 0; kt < KT; kt++) {
    __syncthreads();
    for (int it = 0; it < 4; it++) {
      GLOAD16(Ag + (size_t)it * 32 * K + kt * 64, &As[(w * 8 + it * 32) * 64]);
      GLOAD16(Bg + (size_t)it * 32 * K + kt * 64, &Bs[(w * 8 + it * 32) * 64]);
    }
    __syncthreads();
#pragma unroll
    for (int kkh = 0; kkh < 2; kkh++) {
      int col = (kkh * 32 + lg * 8) ^ cxor;
      bf16x8 af[4], bfr[4];
#pragma unroll
      for (int m = 0; m < 4; m++)
        af[m] = *(const bf16x8*)&As[(wr * 64 + m * 16 + l15) * 64 + col];
#pragma unroll
      for (int n = 0; n < 4; n++)
        bfr[n] = *(const bf16x8*)&Bs[(wc * 64 + n * 16 + l15) * 64 + col];
#pragma unroll
      for (int m = 0; m < 4; m++)
#pragma unroll
        for (int n = 0; n < 4; n++)
          acc[m][n] = __builtin_amdgcn_mfma_f32_16x16x32_bf16(af[m], bfr[n], acc[m][n], 0, 0, 0);
    }
  }

  for (int n = 0; n < 4; n++) {
    int col = n0 + wc * 64 + n * 16 + l15;
    if (MODE == 0) {
      float bval = bias[col];
      int h = col >> 6, d = col & 63;
      for (int m = 0; m < 4; m++) {
        int rowb = m0 + wr * 64 + m * 16 + lg * 4;
        for (int j = 0; j < 4; j++) {
          int row = rowb + j;
          int bb = row >> 11, s = row & 2047;
          outs[(((size_t)bb * NH_ + h) * S_ + s) * HD_ + d] = f2bf((acc[m][n][j] + bval) * qscale);
        }
      }
    } else {
      for (int m = 0; m < 4; m++) {
        int rowb = m0 + wr * 64 + m * 16 + lg * 4;
        for (int j = 0; j < 4; j++)
          youts[(size_t)(rowb + j) * 1024 + col] = acc[m][n][j];
      }
    }
  }
}

// ---------------------------------------------------------------------------
// Kernel 3: flash attention, 32x32x16 MFMA, softmax & P fully in registers.
// Round 7: QTILE=64, 2 waves/block, grid 1024 -> 4 independent blocks/CU
// (4 barrier domains instead of 2; same waves/CU).  Tree max/sum reductions
// (dep depth 32 -> 5).  Ballot prologue split across waves.
//  - q = lane&31 per wave (w*32 rows apart); S^T = mfma_32x32x16(K,Q)
//  - P -> PV B-frags in-register: 4 cvt_pk + 2 permlane32_swap per ks (T12)
//  - K via swizzled global_load_lds dbuf; V subtiled LDS + ds_read_b64_tr_b16
//  - defer-max (T13); single barrier/tile; issue-early/write-late V (T14)
// ---------------------------------------------------------------------------
__global__ __launch_bounds__(128, 2) void attn_kernel(
    const short* __restrict__ Q, const short* __restrict__ K,
    const short* __restrict__ V, const float* __restrict__ mask,
    short* __restrict__ ctx) {
  __shared__ short Ks[2][64 * 64];
  __shared__ short Vs[2][64 * 64];     // subtiled: [kv/4][d/16][4][16]
  __shared__ unsigned long long mbits[32];

  int b = blockIdx.x;
  int bh = (b & 7) * 4 + ((b >> 3) >> 5);   // XCD-grouped: 4 heads per XCD
  int qb = (b >> 3) & 31;
  int bidx = bh >> 4, hh = bh & 15;
  int q0 = qb * 64;
  int tid = threadIdx.x, lane = tid & 63, w = tid >> 6;   // w 0..1
  int l31 = lane & 31, lh = lane >> 5, l15 = lane & 15;

  const short* Qg = Q + (size_t)bh * S_ * HD_;
  const short* Kg = K + (size_t)bh * S_ * HD_;
  const short* Vg = V + (size_t)bh * S_ * HD_;

  int lr = lane >> 3, lc8 = 8 * ((lane & 7) ^ lr);
  int kxor = (lane & 7) * 8;

  // ---- Q fragments straight from global (B-op: col q = w*32+l31) ----
  const short* Qrow = Qg + (size_t)(q0 + w * 32 + l31) * HD_;
  bf16x8 qfrag[4];
#pragma unroll
  for (int ks = 0; ks < 4; ks++)
    qfrag[ks] = *(const bf16x8*)&Qrow[ks * 16 + lh * 8];

  // ---- prologue staging: K tile 0 (swizzled gload_lds), V tile 0, mask ----
#pragma unroll
  for (int it = 0; it < 4; it++) {
    int r = w * 8 + it * 16;
    GLOAD16(Kg + (size_t)(r + lr) * HD_ + lc8, &Ks[0][r * 64]);
  }
  int vrow = tid >> 1, vc0 = (tid & 1) * 32;   // vrow 0..63
  int voff[4];
#pragma unroll
  for (int c = 0; c < 4; c++) {
    int vc = vc0 + c * 8;
    voff[c] = ((vrow >> 2) * 4 + (vc >> 4)) * 64 + (vrow & 3) * 16 + (vc & 15);
    *(int4*)&Vs[0][voff[c]] = *(const int4*)&Vg[(size_t)vrow * HD_ + vc];
  }
  for (int t = w; t < 32; t += 2) {
    unsigned long long bb = __ballot(mask[bidx * S_ + t * 64 + lane] > 0.5f);
    if (lane == 0) mbits[t] = bb;
  }
  __syncthreads();

  float mrun = -1e30f, lrun = 0.f;
  f32x16 oacc[2];
#pragma unroll
  for (int dt = 0; dt < 2; dt++)
#pragma unroll
    for (int j = 0; j < 16; j++) oacc[dt][j] = 0.f;

  unsigned vtrb = (unsigned)(uintptr_t)&Vs[0][0]
                + (unsigned)(l15 * 8 + ((lane >> 4) & 1) * 128 + lh * 1024);

  for (int kt = 0; kt < 32; kt++) {
    int cur = kt & 1;

    // issue next-tile staging early (completes under this tile's compute)
    int4 vp[4];
    if (kt < 31) {
      const short* Kn = Kg + (size_t)(kt + 1) * 64 * HD_;
#pragma unroll
      for (int it = 0; it < 4; it++) {
        int r = w * 8 + it * 16;
        GLOAD16(Kn + (size_t)(r + lr) * HD_ + lc8, &Ks[cur ^ 1][r * 64]);
      }
      const short* Vn = Vg + (size_t)(kt + 1) * 64 * HD_;
#pragma unroll
      for (int c = 0; c < 4; c++)
        vp[c] = *(const int4*)&Vn[(size_t)vrow * HD_ + vc0 + c * 8];
    }

    // ---- S^T = mfma(K, Q): lane q=l31, kv=kb*32+4lh+(r&3)+8(r>>2) ----
    f32x16 sc[2];
#pragma unroll
    for (int kb = 0; kb < 2; kb++)
#pragma unroll
      for (int j = 0; j < 16; j++) sc[kb][j] = 0.f;
    __builtin_amdgcn_s_setprio(1);
#pragma unroll
    for (int ks = 0; ks < 4; ks++)
#pragma unroll
      for (int kb = 0; kb < 2; kb++) {
        bf16x8 af = *(const bf16x8*)&Ks[cur][(kb * 32 + l31) * 64 + ((ks * 16 + lh * 8) ^ kxor)];
        sc[kb] = __builtin_amdgcn_mfma_f32_32x32x16_bf16(af, qfrag[ks], sc[kb], 0, 0, 0);
      }
    __builtin_amdgcn_s_setprio(0);

    // ---- mask (bitmask; all-ones tiles skip entirely) ----
    unsigned long long mb = mbits[kt];
    if (__any(mb != ~0ull)) {
      unsigned long long sh = mb >> (lh * 4);
#pragma unroll
      for (int kb = 0; kb < 2; kb++)
#pragma unroll
        for (int r = 0; r < 16; r++)
          if (!((sh >> (kb * 32 + (r & 3) + 8 * (r >> 2))) & 1)) sc[kb][r] = -1e30f;
    }

    // ---- per-q max: pairwise tree (depth 5) + one permlane32_swap ----
    float rmax;
    {
      float t16[16], t8[8], t4[4], t2[2];
#pragma unroll
      for (int i = 0; i < 16; i++) t16[i] = fmaxf(sc[0][i], sc[1][i]);
#pragma unroll
      for (int i = 0; i < 8; i++) t8[i] = fmaxf(t16[i], t16[i + 8]);
#pragma unroll
      for (int i = 0; i < 4; i++) t4[i] = fmaxf(t8[i], t8[i + 4]);
      t2[0] = fmaxf(t4[0], t4[2]); t2[1] = fmaxf(t4[1], t4[3]);
      rmax = fmaxf(t2[0], t2[1]);
      float xa = rmax, xb = rmax;
      asm volatile("v_permlane32_swap_b32 %0, %1" : "+v"(xa), "+v"(xb));
      rmax = fmaxf(xa, xb);
    }

    // ---- defer-max rescale (T13, THR=8) ----
    if (__any(rmax > mrun + 8.f)) {
      float mn = fmaxf(mrun, rmax);
      float a = EXP2F(mrun - mn);
      lrun *= a; mrun = mn;
#pragma unroll
      for (int dt = 0; dt < 2; dt++)
#pragma unroll
        for (int j = 0; j < 16; j++) oacc[dt][j] *= a;
    }

    // ---- exp2 + tree sum (depth 5) ----
#pragma unroll
    for (int kb = 0; kb < 2; kb++)
#pragma unroll
      for (int r = 0; r < 16; r++)
        sc[kb][r] = EXP2F(sc[kb][r] - mrun);
    float rs_;
    {
      float s16[16], s8[8], s4[4];
#pragma unroll
      for (int i = 0; i < 16; i++) s16[i] = sc[0][i] + sc[1][i];
#pragma unroll
      for (int i = 0; i < 8; i++) s8[i] = s16[i] + s16[i + 8];
#pragma unroll
      for (int i = 0; i < 4; i++) s4[i] = s8[i] + s8[i + 4];
      rs_ = (s4[0] + s4[1]) + (s4[2] + s4[3]);
      float xa = rs_, xb = rs_;
      asm volatile("v_permlane32_swap_b32 %0, %1" : "+v"(xa), "+v"(xb));
      rs_ = xa + xb;
    }
    lrun += rs_;

    // ---- pack P -> PV B-frags in-register (4 cvt_pk + 2 swaps per ks) ----
    bf16x8 pfrag[4];
#pragma unroll
    for (int ks = 0; ks < 4; ks++) {
      int kb = ks >> 1, ro = (ks & 1) * 8;
      unsigned X0, X1, X2, X3;
      asm("v_cvt_pk_bf16_f32 %0, %1, %2" : "=v"(X0) : "v"(sc[kb][ro + 0]), "v"(sc[kb][ro + 1]));
      asm("v_cvt_pk_bf16_f32 %0, %1, %2" : "=v"(X1) : "v"(sc[kb][ro + 2]), "v"(sc[kb][ro + 3]));
      asm("v_cvt_pk_bf16_f32 %0, %1, %2" : "=v"(X2) : "v"(sc[kb][ro + 4]), "v"(sc[kb][ro + 5]));
      asm("v_cvt_pk_bf16_f32 %0, %1, %2" : "=v"(X3) : "v"(sc[kb][ro + 6]), "v"(sc[kb][ro + 7]));
      asm volatile("v_permlane32_swap_b32 %0, %1" : "+v"(X0), "+v"(X2));
      asm volatile("v_permlane32_swap_b32 %0, %1" : "+v"(X1), "+v"(X3));
      union { u32x4 u; bf16x8 b; } cvt;
      cvt.u[0] = X0; cvt.u[1] = X1; cvt.u[2] = X2; cvt.u[3] = X3;
      pfrag[ks] = cvt.b;
    }

    // ---- O^T += V^T P^T: V A-frags via tr-reads, per-dt batches ----
#pragma unroll
    for (int dt = 0; dt < 2; dt++) {
      bf16x4 vlo[4], vhi[4];
#pragma unroll
      for (int ks = 0; ks < 4; ks++) {
        unsigned a = vtrb + (unsigned)(cur * 8192 + ks * 2048 + dt * 256);
        asm volatile("ds_read_b64_tr_b16 %0, %2\n\t"
                     "ds_read_b64_tr_b16 %1, %2 offset:512"
                     : "=&v"(vlo[ks]), "=&v"(vhi[ks]) : "v"(a));
      }
      asm volatile("s_waitcnt lgkmcnt(0)" ::: "memory");
      __builtin_amdgcn_sched_barrier(0);
      __builtin_amdgcn_s_setprio(1);
#pragma unroll
      for (int ks = 0; ks < 4; ks++) {
        bf16x8 vb = __builtin_shufflevector(vlo[ks], vhi[ks], 0, 1, 2, 3, 4, 5, 6, 7);
        oacc[dt] = __builtin_amdgcn_mfma_f32_32x32x16_bf16(vb, pfrag[ks], oacc[dt], 0, 0, 0);
      }
      __builtin_amdgcn_s_setprio(0);
    }

    // write-late V staging for next tile, then the single barrier
    if (kt < 31) {
#pragma unroll
      for (int c = 0; c < 4; c++)
        *(int4*)&Vs[cur ^ 1][voff[c]] = vp[c];
    }
    __syncthreads();
  }

  // epilogue: lane holds O^T col q = q0+w*32+l31; d = dt*32 + 8*rr + 4*lh + j
  float inv = 1.0f / lrun;
  int q = q0 + w * 32 + l31;
  size_t base = ((size_t)(bidx * S_ + q)) * H_ + hh * HD_;
#pragma unroll
  for (int dt = 0; dt < 2; dt++)
#pragma unroll
    for (int rr = 0; rr < 4; rr++) {
      int d0 = dt * 32 + rr * 8 + lh * 4;
      short4 st;
      st.x = f2bf(oacc[dt][rr * 4 + 0] * inv);
      st.y = f2bf(oacc[dt][rr * 4 + 1] * inv);
      st.z = f2bf(oacc[dt][rr * 4 + 2] * inv);
      st.w = f2bf(oacc[dt][rr * 4 + 3] * inv);
      *(short4*)&ctx[base + d0] = st;
    }
}

// ---------------------------------------------------------------------------
// Kernel 5: out = LayerNorm(y0 + y1 + bd + x) * g + b, finite-masked.
// (split-K partials y0,y1; Wd bias bd folded here)
// ---------------------------------------------------------------------------
__global__ __launch_bounds__(256) void ln_kernel(
    const float* __restrict__ y0p, const float* __restrict__ y1p,
    const float* __restrict__ x,   const float* __restrict__ bd,
    const float* __restrict__ g,   const float* __restrict__ bta,
    float* __restrict__ out) {
  __shared__ float red[4];
  int row = blockIdx.x;
  int tid = threadIdx.x, lane = tid & 63, w = tid >> 6;
  size_t base = (size_t)row * 1024 + tid * 4;
  int c = tid * 4;
  float4 y0v = *(const float4*)(y0p + base);
  float4 y1v = *(const float4*)(y1p + base);
  float4 xv  = *(const float4*)(x + base);
  float4 bdv = *(const float4*)(bd + c);
  float v0 = y0v.x + y1v.x + bdv.x + xv.x;
  float v1 = y0v.y + y1v.y + bdv.y + xv.y;
  float v2 = y0v.z + y1v.z + bdv.z + xv.z;
  float v3 = y0v.w + y1v.w + bdv.w + xv.w;

  float ssum = v0 + v1 + v2 + v3;
  for (int off = 1; off < 64; off <<= 1) ssum += __shfl_xor(ssum, off);
  if (lane == 0) red[w] = ssum;
  __syncthreads();
  float mean = (red[0] + red[1] + red[2] + red[3]) * (1.f / 1024.f);
  __syncthreads();

  float d0 = v0 - mean, d1 = v1 - mean, d2 = v2 - mean, d3 = v3 - mean;
  float sq = d0 * d0 + d1 * d1 + d2 * d2 + d3 * d3;
  for (int off = 1; off < 64; off <<= 1) sq += __shfl_xor(sq, off);
  if (lane == 0) red[w] = sq;
  __syncthreads();
  float var = (red[0] + red[1] + red[2] + red[3]) * (1.f / 1024.f);
  float rs = 1.0f / sqrtf(var + 1e-12f);

  float4 gv = *(const float4*)(g + c);
  float4 bv = *(const float4*)(bta + c);
  float o0 = d0 * rs * gv.x + bv.x;
  float o1 = d1 * rs * gv.y + bv.y;
  float o2 = d2 * rs * gv.z + bv.z;
  float o3 = d3 * rs * gv.w + bv.w;
  float4 ov;
  ov.x = __builtin_isfinite(o0) ? o0 : 0.f;
  ov.y = __builtin_isfinite(o1) ? o1 : 0.f;
  ov.z = __builtin_isfinite(o2) ? o2 : 0.f;
  ov.w = __builtin_isfinite(o3) ? o3 : 0.f;
  *(float4*)(out + base) = ov;
}

// ---------------------------------------------------------------------------
extern "C" void kernel_launch(void* const* d_in, const int* in_sizes, int n_in,
                              void* d_out, int out_size, void* d_ws, size_t ws_size,
                              hipStream_t stream) {
  (void)in_sizes; (void)n_in; (void)out_size; (void)ws_size;
  const float* x    = (const float*)d_in[0];
  const float* mask = (const float*)d_in[1];
  const float* Wq   = (const float*)d_in[2];
  const float* bq   = (const float*)d_in[3];
  const float* Wk   = (const float*)d_in[4];
  const float* bk   = (const float*)d_in[5];
  const float* Wv   = (const float*)d_in[6];
  const float* bv   = (const float*)d_in[7];
  const float* Wd   = (const float*)d_in[8];
  const float* bd   = (const float*)d_in[9];
  const float* ln_g = (const float*)d_in[10];
  const float* ln_b = (const float*)d_in[11];
  float* out = (float*)d_out;

  char* ws = (char*)d_ws;
  short* xb   = (short*)(ws);                       //  8 MB  x bf16
  short* wqb  = (short*)(ws + ( 8ull << 20));       //  2 MB
  short* wkb  = (short*)(ws + (10ull << 20));       //  2 MB
  short* wvb  = (short*)(ws + (12ull << 20));       //  2 MB
  short* wdb  = (short*)(ws + (14ull << 20));       //  2 MB
  short* qb   = (short*)(ws + (16ull << 20));       //  8 MB  [B,NH,S,HD]
  short* kb   = (short*)(ws + (24ull << 20));       //  8 MB
  short* vb   = (short*)(ws + (32ull << 20));       //  8 MB
  short* ctxb = (short*)(ws + (40ull << 20));       //  8 MB  [B,S,H]
  float* y0   = (float*)(ws + (48ull << 20));       // 16 MB  fp32 partial
  float* y1   = (float*)(ws + (16ull << 20));       // 16 MB  aliases qb+kb (dead after attn)

  convert_kernel<<<8192, 256, 0, stream>>>(x, Wq, Wk, Wv, Wd, xb, wqb, wkb, wvb, wdb);
  gemm_bt<0><<<dim3(8, 32, 3), 256, 0, stream>>>(xb, wqb, wkb, wvb, bq, bk, bv,
                                                 qb, kb, vb, nullptr, nullptr);
  attn_kernel<<<1024, 128, 0, stream>>>(qb, kb, vb, mask, ctxb);
  gemm_bt<1><<<dim3(8, 32, 2), 256, 0, stream>>>(ctxb, wdb, nullptr, nullptr, nullptr,
                                                 nullptr, nullptr, nullptr, nullptr,
                                                 nullptr, y0, y1);
  ln_kernel<<<4096, 256, 0, stream>>>(y0, y1, x, bd, ln_g, ln_b, out);
}